// Round 11
// baseline (488.195 us; speedup 1.0000x reference)
//
#include <hip/hip_runtime.h>

typedef unsigned short u16;
typedef short s16x8 __attribute__((ext_vector_type(8)));
typedef float f32x4 __attribute__((ext_vector_type(4)));

#define DEVI static __device__ __forceinline__
#define MFMA16(A, B, C) __builtin_amdgcn_mfma_f32_16x16x32_bf16(A, B, C, 0, 0, 0)
#define Z4 ((f32x4){0.f, 0.f, 0.f, 0.f})

DEVI float bf2f(u16 u) {
  __bf16 h; __builtin_memcpy(&h, &u, 2); return (float)h;
}
DEVI u16 f2bf(float f) {
  __bf16 h = (__bf16)f;
  u16 u; __builtin_memcpy(&u, &h, 2); return u;
}
DEVI float rcpf_(float x) { return __builtin_amdgcn_rcpf(x); }
DEVI float sigmoidf_(float x) { return rcpf_(1.0f + __expf(-x)); }
DEVI float tanhf_(float x) { return 1.0f - 2.0f * rcpf_(__expf(2.0f * x) + 1.0f); }

// =================================================================
// k_wconv: f32 weights -> bf16, FRAGMENT-MAJOR packed:
//   P[ct][ks][kg][lr][j] = W[ct*16+lr][ks*32+kg*8+j]
// (B-fragment load = 1KB contiguous). Packs in_proj, out_w, w_hh.
// (lin_w / w_ih are consumed only via Wcomb -> k_wcomb.)
// =================================================================
__global__ void k_wconv(const float* __restrict__ w0, const float* __restrict__ w1,
                        const float* __restrict__ w4, u16* __restrict__ out) {
  int c = blockIdx.x * 256 + threadIdx.x;
  if (c >= 57344) return;
  const float* src; long base; int cl;
  if (c < 24576)      { src = w0; base = 0;      cl = c; }
  else if (c < 32768) { src = w1; base = 196608; cl = c - 24576; }
  else                { src = w4; base = 458752; cl = c - 32768; }
  int lr = cl & 15, kg = (cl >> 4) & 3, ks = (cl >> 6) & 7, ct = cl >> 9;
  const float* sp = src + (ct * 16 + lr) * 256 + ks * 32 + kg * 8;
  f32x4 v0 = *(const f32x4*)sp;
  f32x4 v1 = *(const f32x4*)(sp + 4);
  s16x8 t;
  t[0] = (short)f2bf(v0[0]); t[1] = (short)f2bf(v0[1]);
  t[2] = (short)f2bf(v0[2]); t[3] = (short)f2bf(v0[3]);
  t[4] = (short)f2bf(v1[0]); t[5] = (short)f2bf(v1[1]);
  t[6] = (short)f2bf(v1[2]); t[7] = (short)f2bf(v1[3]);
  *(s16x8*)(out + base + (long)cl * 8) = t;
}

// =================================================================
// k_wcomb: GEMM fold. gi = inter@Wih^T+bih, inter = H@Wlin^T+blin
//   => gi = H@Wcomb^T + bcomb,  Wcomb = Wih@Wlin (768x256, f32),
//      bcomb = Wih@blin + bih.
// One block per output row i; f32 accumulate; emit packed bf16.
// =================================================================
__global__ __launch_bounds__(256) void k_wcomb(
    const float* __restrict__ w_ih, const float* __restrict__ lin_w,
    const float* __restrict__ b_lin, const float* __restrict__ b_ih,
    u16* __restrict__ outw, float* __restrict__ outb) {
  __shared__ float row[256];
  int i = blockIdx.x;            // 0..767
  int tid = threadIdx.x;         // output col j
  row[tid] = w_ih[i * 256 + tid];
  __syncthreads();
  float acc = 0.f;
#pragma unroll 8
  for (int o = 0; o < 256; ++o) acc += row[o] * lin_w[o * 256 + tid];
  int ct = i >> 4, lr = i & 15;
  int ks = tid >> 5, kg = (tid >> 3) & 3, jj = tid & 7;
  long cl = (ct * 8 + ks) * 64 + kg * 16 + lr;
  outw[cl * 8 + jj] = f2bf(acc);
  if (tid == 0) {
    float s = 0.f;
    for (int o = 0; o < 256; ++o) s += row[o] * b_lin[o];
    outb[i] = s + b_ih[i];
  }
}

// =================================================================
// k_tr: (b,s,e) f32 -> (s,b,e) bf16 with the 2x fused-identity factor
// folded in. (Channel/spatial attention collapse to identity:
// softmax over size-1 axes == 1, so fused = 2*input exactly.)
// =================================================================
__global__ void k_tr(const float* __restrict__ text, const float* __restrict__ graph,
                     u16* __restrict__ T2T, u16* __restrict__ T2G) {
  long idx = (long)blockIdx.x * 256 + threadIdx.x;
  int side = (int)(idx >> 21);
  long r = (idx >> 5) & 65535;   // input row = b*2048 + s
  int c8 = (int)(idx & 31);
  long b = r >> 11, s = r & 2047;
  const float* src = (side ? graph : text) + r * 256 + c8 * 8;
  u16* dst = (side ? T2G : T2T) + ((s << 5) + b) * 256 + c8 * 8;
  f32x4 v0 = *(const f32x4*)src;
  f32x4 v1 = *(const f32x4*)(src + 4);
  s16x8 t;
  t[0] = (short)f2bf(2.f * v0[0]); t[1] = (short)f2bf(2.f * v0[1]);
  t[2] = (short)f2bf(2.f * v0[2]); t[3] = (short)f2bf(2.f * v0[3]);
  t[4] = (short)f2bf(2.f * v1[0]); t[5] = (short)f2bf(2.f * v1[1]);
  t[6] = (short)f2bf(2.f * v1[2]); t[7] = (short)f2bf(2.f * v1[3]);
  *(s16x8*)dst = t;
}

// =================================================================
// Phase 1: per-(s,side) block: K/Q/V proj -> QK^T -> softmax -> PV
// -> out-proj. 4096 blocks x 256 thr (4 waves).
// att output now in (s,b,e) layout -> final write is ONE contiguous
// 16KB block (GRU is row-order independent, so this is free).
// =================================================================
#define AOo 0
#define AXo 8448
#define KBo 16896
#define QBo 25344
#define SFo 33792
#define PBo 35904
#define VTo 8448
#define OBo 25344
#define STo 16896

__global__ __launch_bounds__(256, 2) void k_attn(
    const u16* __restrict__ T2T, const u16* __restrict__ T2G,
    const u16* __restrict__ Wproj, const float* __restrict__ bproj,
    const u16* __restrict__ Wout, const float* __restrict__ bout,
    u16* __restrict__ attT, u16* __restrict__ attG) {
  __shared__ u16 sh[37184];
  int n = blockIdx.x, s = blockIdx.y;
  const u16* pown = (s ? T2G : T2T) + n * 8192;
  const u16* poth = (s ? T2T : T2G) + n * 8192;
  u16* dst = s ? attG : attT;
  int tid = threadIdx.x, w = tid >> 6, lane = tid & 63;
  int lr = lane & 15, kg = lane >> 4;
  int fro = ((kg << 4) + lr) * 8;  // in-fragment offset for packed B

  // ---- ph1: cooperative 16KB panel loads (coalesced) ----
  {
    int r = tid >> 3, c0 = (tid & 7) * 32;
    const u16* so = pown + r * 256 + c0;
    const u16* sx = poth + r * 256 + c0;
    u16* d0 = sh + AOo + r * 264 + c0;
    u16* d1 = sh + AXo + r * 264 + c0;
#pragma unroll
    for (int j = 0; j < 4; ++j) {
      *(s16x8*)(d0 + j * 8) = *(const s16x8*)(so + j * 8);
      *(s16x8*)(d1 + j * 8) = *(const s16x8*)(sx + j * 8);
    }
  }
  __syncthreads();

  s16x8 af[2][8];  // A fragments (AX for K, then AO for Q/V)

  // ---- ph2a: K-proj from other-side panel (W cols 256..511) ----
#pragma unroll
  for (int mt = 0; mt < 2; ++mt)
#pragma unroll
    for (int k = 0; k < 8; ++k)
      af[mt][k] = *(const s16x8*)(sh + AXo + (mt * 16 + lr) * 264 + k * 32 + kg * 8);
  for (int i = 0; i < 4; ++i) {
    int ct = 16 + w * 4 + i;
    const u16* wp = Wproj + (ct << 12) + fro;
    s16x8 b[8];
#pragma unroll
    for (int k = 0; k < 8; ++k) b[k] = *(const s16x8*)(wp + (k << 9));
    f32x4 a0 = Z4, a1 = Z4;
#pragma unroll
    for (int k = 0; k < 8; ++k) {
      a0 = MFMA16(af[0][k], b[k], a0);
      a1 = MFMA16(af[1][k], b[k], a1);
    }
    int colk = (ct << 4) + lr;
    float bias = bproj[colk];
    u16* base = sh + KBo + (colk - 256);
#pragma unroll
    for (int j = 0; j < 4; ++j) {
      base[(kg * 4 + j) * 264] = f2bf(a0[j] + bias);
      base[(16 + kg * 4 + j) * 264] = f2bf(a1[j] + bias);
    }
  }

  // ---- ph2b: Q-proj from own-side panel (W cols 0..255) ----
#pragma unroll
  for (int mt = 0; mt < 2; ++mt)
#pragma unroll
    for (int k = 0; k < 8; ++k)
      af[mt][k] = *(const s16x8*)(sh + AOo + (mt * 16 + lr) * 264 + k * 32 + kg * 8);
  for (int i = 0; i < 4; ++i) {
    int ct = w * 4 + i;
    const u16* wp = Wproj + (ct << 12) + fro;
    s16x8 b[8];
#pragma unroll
    for (int k = 0; k < 8; ++k) b[k] = *(const s16x8*)(wp + (k << 9));
    f32x4 a0 = Z4, a1 = Z4;
#pragma unroll
    for (int k = 0; k < 8; ++k) {
      a0 = MFMA16(af[0][k], b[k], a0);
      a1 = MFMA16(af[1][k], b[k], a1);
    }
    int colq = (ct << 4) + lr;
    float bias = bproj[colq];
    u16* base = sh + QBo + colq;
#pragma unroll
    for (int j = 0; j < 4; ++j) {
      base[(kg * 4 + j) * 264] = f2bf(a0[j] + bias);
      base[(16 + kg * 4 + j) * 264] = f2bf(a1[j] + bias);
    }
  }
  __syncthreads();

  // ---- ph3: scores S[l][m] = Q.K^T / 16 ----
  {
    int mt = w >> 1, nt = w & 1;
    f32x4 acc = Z4;
#pragma unroll
    for (int k = 0; k < 8; ++k) {
      s16x8 qa = *(const s16x8*)(sh + QBo + (mt * 16 + lr) * 264 + k * 32 + kg * 8);
      s16x8 kb = *(const s16x8*)(sh + KBo + (nt * 16 + lr) * 264 + k * 32 + kg * 8);
      acc = MFMA16(qa, kb, acc);
    }
    float* Sf = (float*)(sh + SFo);
#pragma unroll
    for (int j = 0; j < 4; ++j)
      Sf[(mt * 16 + kg * 4 + j) * 33 + nt * 16 + lr] = acc[j] * 0.0625f;
  }
  __syncthreads();

  // ---- ph4: V-proj (af=AO still live; W cols 512..767) + softmax ----
  for (int i = 0; i < 4; ++i) {
    int ct = 32 + w * 4 + i;
    const u16* wp = Wproj + (ct << 12) + fro;
    s16x8 b[8];
#pragma unroll
    for (int k = 0; k < 8; ++k) b[k] = *(const s16x8*)(wp + (k << 9));
    f32x4 a0 = Z4, a1 = Z4;
#pragma unroll
    for (int k = 0; k < 8; ++k) {
      a0 = MFMA16(af[0][k], b[k], a0);
      a1 = MFMA16(af[1][k], b[k], a1);
    }
    int colv = (ct << 4) + lr;
    float bias = bproj[colv];
    u16* base = sh + VTo + (colv - 512) * 40;
#pragma unroll
    for (int j = 0; j < 4; ++j) {
      base[kg * 4 + j] = f2bf(a0[j] + bias);
      base[16 + kg * 4 + j] = f2bf(a1[j] + bias);
    }
  }
  if (tid < 32) {
    float* Sp = (float*)(sh + SFo) + tid * 33;
    float mx = -1e30f;
#pragma unroll
    for (int m = 0; m < 32; ++m) mx = fmaxf(mx, Sp[m]);
    float e[32]; float sum = 0.f;
#pragma unroll
    for (int m = 0; m < 32; ++m) { e[m] = __expf(Sp[m] - mx); sum += e[m]; }
    float inv = rcpf_(sum);
    u16* Pp = sh + PBo + tid * 40;
#pragma unroll
    for (int m = 0; m < 32; ++m) Pp[m] = f2bf(e[m] * inv);
  }
  __syncthreads();

  // ---- ph5: PV: O = P.V -> OB ----
  {
    s16x8 pa0 = *(const s16x8*)(sh + PBo + lr * 40 + kg * 8);
    s16x8 pa1 = *(const s16x8*)(sh + PBo + (16 + lr) * 40 + kg * 8);
#pragma unroll
    for (int i = 0; i < 4; ++i) {
      int e0 = (w * 4 + i) * 16;
      s16x8 vb = *(const s16x8*)(sh + VTo + (e0 + lr) * 40 + kg * 8);
      f32x4 a0 = MFMA16(pa0, vb, Z4);
      f32x4 a1 = MFMA16(pa1, vb, Z4);
      u16* base = sh + OBo + e0 + lr;
#pragma unroll
      for (int j = 0; j < 4; ++j) {
        base[(kg * 4 + j) * 264] = f2bf(a0[j]);
        base[(16 + kg * 4 + j) * 264] = f2bf(a1[j]);
      }
    }
  }
  __syncthreads();

  // ---- ph6: out-proj -> ST staging -> ONE contiguous 16KB write ----
  {
    s16x8 ao[2][8];
#pragma unroll
    for (int mt = 0; mt < 2; ++mt)
#pragma unroll
      for (int k = 0; k < 8; ++k)
        ao[mt][k] = *(const s16x8*)(sh + OBo + (mt * 16 + lr) * 264 + k * 32 + kg * 8);
    for (int i = 0; i < 4; ++i) {
      int ct = w * 4 + i;
      const u16* wp = Wout + (ct << 12) + fro;
      s16x8 b[8];
#pragma unroll
      for (int k = 0; k < 8; ++k) b[k] = *(const s16x8*)(wp + (k << 9));
      f32x4 a0 = Z4, a1 = Z4;
#pragma unroll
      for (int k = 0; k < 8; ++k) {
        a0 = MFMA16(ao[0][k], b[k], a0);
        a1 = MFMA16(ao[1][k], b[k], a1);
      }
      int cb = (ct << 4) + lr;
      float bias = bout[cb];
      u16* base = sh + STo + cb;
#pragma unroll
      for (int j = 0; j < 4; ++j) {
        base[(kg * 4 + j) * 264] = f2bf(a0[j] + bias);
        base[(16 + kg * 4 + j) * 264] = f2bf(a1[j] + bias);
      }
    }
  }
  __syncthreads();
  {
    int r = tid >> 3, c0 = (tid & 7) * 32;
    u16* dr = dst + ((long)n << 13) + r * 256 + c0;  // (s,b,e): contiguous
#pragma unroll
    for (int j = 0; j < 4; ++j)
      *(s16x8*)(dr + j * 8) = *(const s16x8*)(sh + STo + r * 264 + c0 + j * 8);
  }
}

// =================================================================
// Phase 2: H=attT*attG -> gates (gi via folded Wcomb) -> GRU.
// 2048 blocks x 32 rows (rows = (s,b) pairs; GRU is row-independent),
// 512 thr / 8 waves; wave = 32 rows x 32 cols, B reg-dbuf.
// No inter GEMM, no HI buffer: aI operands come from aH registers.
// LDS: AT @0, AG @8448 = 33.8 KB.
// =================================================================
__global__ __launch_bounds__(512, 1) void k_gru(
    const u16* __restrict__ attT, const u16* __restrict__ attG,
    const u16* __restrict__ Wcomb, const float* __restrict__ bcomb,
    const u16* __restrict__ Whh, const float* __restrict__ bhh,
    u16* __restrict__ g1, u16* __restrict__ g2) {
  __shared__ u16 sh[16896];
  const int AT = 0, AG = 8448;
  int m0 = blockIdx.x * 32;
  int tid = threadIdx.x, w = tid >> 6, lane = tid & 63;
  int lr = lane & 15, kg = lane >> 4;
  int fro = ((kg << 4) + lr) * 8;

  // cooperative att load (coalesced, non-temporal)
  {
    int r = tid >> 4, c0 = (tid & 15) * 16;
    const u16* pt = attT + (m0 + r) * 256 + c0;
    const u16* pg = attG + (m0 + r) * 256 + c0;
    *(s16x8*)(sh + AT + r * 264 + c0) = __builtin_nontemporal_load((const s16x8*)pt);
    *(s16x8*)(sh + AT + r * 264 + c0 + 8) = __builtin_nontemporal_load((const s16x8*)(pt + 8));
    *(s16x8*)(sh + AG + r * 264 + c0) = __builtin_nontemporal_load((const s16x8*)pg);
    *(s16x8*)(sh + AG + r * 264 + c0 + 8) = __builtin_nontemporal_load((const s16x8*)(pg + 8));
  }
  __syncthreads();

  // H fragments (rows mt*16+lr) — live through the gate phase (aI operand)
  s16x8 aH[2][8];
#pragma unroll
  for (int mt = 0; mt < 2; ++mt)
#pragma unroll
    for (int k = 0; k < 8; ++k) {
      s16x8 t8 = *(const s16x8*)(sh + AT + (mt * 16 + lr) * 264 + k * 32 + kg * 8);
      s16x8 g8 = *(const s16x8*)(sh + AG + (mt * 16 + lr) * 264 + k * 32 + kg * 8);
      s16x8 h;
#pragma unroll
      for (int j = 0; j < 8; ++j)
        h[j] = (short)f2bf(bf2f((u16)t8[j]) * bf2f((u16)g8[j]));
      aH[mt][k] = h;
    }

#define LDGATE(slot, kk) { \
    int fo_ = ((kk) << 9) + fro; \
    bI[slot][0] = *(const s16x8*)(Wcomb + (ct0 << 12) + fo_); \
    bI[slot][1] = *(const s16x8*)(Wcomb + (ct1 << 12) + fo_); \
    bI[slot][2] = *(const s16x8*)(Wcomb + (ct2 << 12) + fo_); \
    bH[slot][0] = *(const s16x8*)(Whh + (ct0 << 12) + fo_); \
    bH[slot][1] = *(const s16x8*)(Whh + (ct1 << 12) + fo_); \
    bH[slot][2] = *(const s16x8*)(Whh + (ct2 << 12) + fo_); }

  // gate GEMMs (B reg-dbuf) + GRU elementwise -> reg buffers
  s16x8 o1b[2], o2b[2];
#pragma unroll
  for (int ic = 0; ic < 2; ++ic) {
    int ct0 = w * 2 + ic, ct1 = 16 + ct0, ct2 = 32 + ct0;
    int col = (ct0 << 4) + lr;
    f32x4 acc[3][3][2];
#pragma unroll
    for (int g = 0; g < 3; ++g)
#pragma unroll
      for (int s2 = 0; s2 < 3; ++s2) { acc[g][s2][0] = Z4; acc[g][s2][1] = Z4; }
    s16x8 bI[2][3], bH[2][3];
    LDGATE(0, 0)
#pragma unroll
    for (int k = 0; k < 8; ++k) {
      const int c = k & 1, nx = c ^ 1;
      if (k < 7) { LDGATE(nx, k + 1) }
      int ko = k * 32 + kg * 8;
      s16x8 aT0 = *(const s16x8*)(sh + AT + lr * 264 + ko);
      s16x8 aT1 = *(const s16x8*)(sh + AT + (16 + lr) * 264 + ko);
      s16x8 aG0 = *(const s16x8*)(sh + AG + lr * 264 + ko);
      s16x8 aG1 = *(const s16x8*)(sh + AG + (16 + lr) * 264 + ko);
#pragma unroll
      for (int g = 0; g < 3; ++g) {
        acc[g][0][0] = MFMA16(aH[0][k], bI[c][g], acc[g][0][0]);
        acc[g][0][1] = MFMA16(aH[1][k], bI[c][g], acc[g][0][1]);
        acc[g][1][0] = MFMA16(aT0, bH[c][g], acc[g][1][0]);
        acc[g][1][1] = MFMA16(aT1, bH[c][g], acc[g][1][1]);
        acc[g][2][0] = MFMA16(aG0, bH[c][g], acc[g][2][0]);
        acc[g][2][1] = MFMA16(aG1, bH[c][g], acc[g][2][1]);
      }
    }
    float bir = bcomb[col], biz = bcomb[col + 256], bin_ = bcomb[col + 512];
    float bhr = bhh[col], bhz = bhh[col + 256], bhn = bhh[col + 512];
    s16x8 o1v, o2v;
#pragma unroll
    for (int mt = 0; mt < 2; ++mt)
#pragma unroll
      for (int j = 0; j < 4; ++j) {
        int row = mt * 16 + kg * 4 + j;
        float hT = bf2f(sh[AT + row * 264 + col]);
        float hG = bf2f(sh[AG + row * 264 + col]);
        float ir = acc[0][0][mt][j] + bir;
        float iz = acc[1][0][mt][j] + biz;
        float inn = acc[2][0][mt][j] + bin_;
        float r1 = sigmoidf_(ir + acc[0][1][mt][j] + bhr);
        float z1 = sigmoidf_(iz + acc[1][1][mt][j] + bhz);
        float n1 = tanhf_(inn + r1 * (acc[2][1][mt][j] + bhn));
        o1v[mt * 4 + j] = (short)f2bf((1.f - z1) * n1 + z1 * hT);
        float r2 = sigmoidf_(ir + acc[0][2][mt][j] + bhr);
        float z2 = sigmoidf_(iz + acc[1][2][mt][j] + bhz);
        float n2 = tanhf_(inn + r2 * (acc[2][2][mt][j] + bhn));
        o2v[mt * 4 + j] = (short)f2bf((1.f - z2) * n2 + z2 * hG);
      }
    o1b[ic] = o1v; o2b[ic] = o2v;
  }
  __syncthreads();  // all AT/AG reads complete

  // stage outputs into AT/AG (now dead), then coalesced global writes
#pragma unroll
  for (int ic = 0; ic < 2; ++ic) {
    int col = ((w * 2 + ic) << 4) + lr;
#pragma unroll
    for (int mt = 0; mt < 2; ++mt)
#pragma unroll
      for (int j = 0; j < 4; ++j) {
        int row = mt * 16 + kg * 4 + j;
        sh[AT + row * 264 + col] = (u16)o1b[ic][mt * 4 + j];
        sh[AG + row * 264 + col] = (u16)o2b[ic][mt * 4 + j];
      }
  }
  __syncthreads();
  {
    int r = tid >> 4, c0 = (tid & 15) * 16;
    u16* p1 = g1 + (long)(m0 + r) * 256 + c0;
    u16* p2 = g2 + (long)(m0 + r) * 256 + c0;
    *(s16x8*)(p1) = *(const s16x8*)(sh + AT + r * 264 + c0);
    *(s16x8*)(p1 + 8) = *(const s16x8*)(sh + AT + r * 264 + c0 + 8);
    *(s16x8*)(p2) = *(const s16x8*)(sh + AG + r * 264 + c0);
    *(s16x8*)(p2 + 8) = *(const s16x8*)(sh + AG + r * 264 + c0 + 8);
  }
}

// =================================================================
// Phase 3: out = relu(conv7x7(g1)+b) + relu(conv7x7(g2)+b), f32 out.
// g1/g2 are in (s,b,e) layout; out stays (b,s,e) f32.
// =================================================================
__global__ __launch_bounds__(256) void k_conv(
    const u16* __restrict__ g1, const u16* __restrict__ g2,
    const float* __restrict__ wss, const float* __restrict__ bss,
    float* __restrict__ out) {
  __shared__ float s1[38][73];
  __shared__ float s2[38][73];
  int et = blockIdx.x, st = blockIdx.y, b = blockIdx.z;
  int s0 = st * 32, e0 = et * 64;
  int tid = threadIdx.x;
  for (int idx = tid; idx < 38 * 70; idx += 256) {
    int r = idx / 70, c = idx % 70;
    int s = s0 + r - 3, e = e0 + c - 3;
    float v1 = 0.f, v2 = 0.f;
    if (s >= 0 && s < 2048 && e >= 0 && e < 256) {
      long off = ((long)s * 32 + b) * 256 + e;  // (s,b,e)
      v1 = bf2f(g1[off]); v2 = bf2f(g2[off]);
    }
    s1[r][c] = v1; s2[r][c] = v2;
  }
  __syncthreads();
  float bias = bss[0];
  int oy = tid >> 3, ox = (tid & 7) * 8;
  float a1[8] = {0.f, 0.f, 0.f, 0.f, 0.f, 0.f, 0.f, 0.f};
  float a2[8] = {0.f, 0.f, 0.f, 0.f, 0.f, 0.f, 0.f, 0.f};
#pragma unroll
  for (int ky = 0; ky < 7; ++ky) {
    float wr[7];
#pragma unroll
    for (int kx = 0; kx < 7; ++kx) wr[kx] = wss[ky * 7 + kx];
    float r1[14], r2[14];
#pragma unroll
    for (int j = 0; j < 14; ++j) { r1[j] = s1[oy + ky][ox + j]; r2[j] = s2[oy + ky][ox + j]; }
#pragma unroll
    for (int x = 0; x < 8; ++x)
#pragma unroll
      for (int kx = 0; kx < 7; ++kx) {
        a1[x] += r1[x + kx] * wr[kx];
        a2[x] += r2[x + kx] * wr[kx];
      }
  }
  long obase = ((long)b * 2048 + s0 + oy) * 256 + e0 + ox;
  f32x4 o0, o1;
#pragma unroll
  for (int x = 0; x < 4; ++x) {
    o0[x] = fmaxf(a1[x] + bias, 0.f) + fmaxf(a2[x] + bias, 0.f);
    o1[x] = fmaxf(a1[x + 4] + bias, 0.f) + fmaxf(a2[x + 4] + bias, 0.f);
  }
  *(f32x4*)(out + obase) = o0;
  *(f32x4*)(out + obase + 4) = o1;
}

extern "C" void kernel_launch(void* const* d_in, const int* in_sizes, int n_in,
                              void* d_out, int out_size, void* d_ws, size_t ws_size,
                              hipStream_t stream) {
  const float* text = (const float*)d_in[0];
  const float* graph = (const float*)d_in[1];
  // d_in[2..7] (avg_*/max_*/sp_*) are mathematically dead:
  // softmax over size-1 axes == 1 -> fused = 2*input exactly.
  const float* in_proj_w = (const float*)d_in[8];
  const float* in_proj_b = (const float*)d_in[9];
  const float* out_w = (const float*)d_in[10];
  const float* out_b = (const float*)d_in[11];
  const float* lin_w = (const float*)d_in[12];
  const float* lin_b = (const float*)d_in[13];
  const float* w_ih = (const float*)d_in[14];
  const float* w_hh = (const float*)d_in[15];
  const float* b_ih = (const float*)d_in[16];
  const float* b_hh = (const float*)d_in[17];
  const float* ssf_w = (const float*)d_in[18];
  const float* ssf_b = (const float*)d_in[19];

  // ws: g1 (32MB) | g2 (32MB) | packed bf16 weights (1.31MB) | bcomb f32
  // T2T/T2G (pre-transposed inputs) ALIAS g1/g2 (disjoint lifetimes).
  u16* g1 = (u16*)d_ws;
  u16* g2 = g1 + 16777216;
  u16* T2T = g1;
  u16* T2G = g2;
  u16* Wall = g2 + 16777216;
  u16* Wproj = Wall;                 // 196608
  u16* Wout = Wall + 196608;         // 65536
  u16* Wcomb = Wall + 262144;        // 196608 (Wih@Wlin, packed)
  u16* Whh = Wall + 458752;          // 196608
  float* bcomb = (float*)(Wall + 655360);  // 768 f32

  // d_out (64MB f32) doubles as bf16 scratch for attT/attG (s,b,e);
  // k_conv fully rewrites it as f32 at the end.
  u16* attT = (u16*)d_out;
  u16* attG = attT + 16777216;

  k_wconv<<<224, 256, 0, stream>>>(in_proj_w, out_w, w_hh, Wall);
  k_wcomb<<<768, 256, 0, stream>>>(w_ih, lin_w, lin_b, b_ih, Wcomb, bcomb);
  k_tr<<<16384, 256, 0, stream>>>(text, graph, T2T, T2G);

  k_attn<<<dim3(2048, 2), 256, 0, stream>>>(T2T, T2G, Wproj, in_proj_b, Wout, out_b, attT, attG);
  k_gru<<<2048, 512, 0, stream>>>(attT, attG, Wcomb, bcomb, Whh, b_hh, g1, g2);
  k_conv<<<dim3(4, 64, 32), 256, 0, stream>>>(g1, g2, ssf_w, ssf_b, (float*)d_out);
}

// Round 12
// 374.761 us; speedup vs baseline: 1.3027x; 1.3027x over previous
//
#include <hip/hip_runtime.h>

typedef unsigned short u16;
typedef short s16x8 __attribute__((ext_vector_type(8)));
typedef float f32x4 __attribute__((ext_vector_type(4)));

#define DEVI static __device__ __forceinline__
#define MFMA16(A, B, C) __builtin_amdgcn_mfma_f32_16x16x32_bf16(A, B, C, 0, 0, 0)
#define Z4 ((f32x4){0.f, 0.f, 0.f, 0.f})

DEVI float bf2f(u16 u) {
  __bf16 h; __builtin_memcpy(&h, &u, 2); return (float)h;
}
DEVI u16 f2bf(float f) {
  __bf16 h = (__bf16)f;
  u16 u; __builtin_memcpy(&u, &h, 2); return u;
}
DEVI float rcpf_(float x) { return __builtin_amdgcn_rcpf(x); }
DEVI float sigmoidf_(float x) { return rcpf_(1.0f + __expf(-x)); }
DEVI float tanhf_(float x) { return 1.0f - 2.0f * rcpf_(__expf(2.0f * x) + 1.0f); }

// =================================================================
// k_wconv: f32 weights -> bf16, FRAGMENT-MAJOR packed:
//   P[ct][ks][kg][lr][j] = W[ct*16+lr][ks*32+kg*8+j]
// (B-fragment load = 1KB contiguous). Packs in_proj, out_w, w_hh.
// =================================================================
__global__ void k_wconv(const float* __restrict__ w0, const float* __restrict__ w1,
                        const float* __restrict__ w4, u16* __restrict__ out) {
  int c = blockIdx.x * 256 + threadIdx.x;
  if (c >= 57344) return;
  const float* src; long base; int cl;
  if (c < 24576)      { src = w0; base = 0;      cl = c; }
  else if (c < 32768) { src = w1; base = 196608; cl = c - 24576; }
  else                { src = w4; base = 458752; cl = c - 32768; }
  int lr = cl & 15, kg = (cl >> 4) & 3, ks = (cl >> 6) & 7, ct = cl >> 9;
  const float* sp = src + (ct * 16 + lr) * 256 + ks * 32 + kg * 8;
  f32x4 v0 = *(const f32x4*)sp;
  f32x4 v1 = *(const f32x4*)(sp + 4);
  s16x8 t;
  t[0] = (short)f2bf(v0[0]); t[1] = (short)f2bf(v0[1]);
  t[2] = (short)f2bf(v0[2]); t[3] = (short)f2bf(v0[3]);
  t[4] = (short)f2bf(v1[0]); t[5] = (short)f2bf(v1[1]);
  t[6] = (short)f2bf(v1[2]); t[7] = (short)f2bf(v1[3]);
  *(s16x8*)(out + base + (long)cl * 8) = t;
}

// =================================================================
// k_wcomb: GEMM fold. gi = inter@Wih^T+bih, inter = H@Wlin^T+blin
//   => gi = H@Wcomb^T + bcomb,  Wcomb = Wih@Wlin (768x256, f32),
//      bcomb = Wih@blin + bih. Emits fragment-major packed bf16.
// =================================================================
__global__ __launch_bounds__(256) void k_wcomb(
    const float* __restrict__ w_ih, const float* __restrict__ lin_w,
    const float* __restrict__ b_lin, const float* __restrict__ b_ih,
    u16* __restrict__ outw, float* __restrict__ outb) {
  __shared__ float row[256];
  int i = blockIdx.x;            // 0..767
  int tid = threadIdx.x;         // output col j
  row[tid] = w_ih[i * 256 + tid];
  __syncthreads();
  float acc = 0.f;
#pragma unroll 8
  for (int o = 0; o < 256; ++o) acc += row[o] * lin_w[o * 256 + tid];
  int ct = i >> 4, lr = i & 15;
  int ks = tid >> 5, kg = (tid >> 3) & 3, jj = tid & 7;
  long cl = (ct * 8 + ks) * 64 + kg * 16 + lr;
  outw[cl * 8 + jj] = f2bf(acc);
  if (tid == 0) {
    float s = 0.f;
    for (int o = 0; o < 256; ++o) s += row[o] * b_lin[o];
    outb[i] = s + b_ih[i];
  }
}

// =================================================================
// k_tr: (b,s,e) f32 -> (s,b,e) bf16 with the 2x fused-identity factor
// folded in. (Channel/spatial attention collapse to identity:
// softmax over size-1 axes == 1, so fused = 2*input exactly.)
// =================================================================
__global__ void k_tr(const float* __restrict__ text, const float* __restrict__ graph,
                     u16* __restrict__ T2T, u16* __restrict__ T2G) {
  long idx = (long)blockIdx.x * 256 + threadIdx.x;
  int side = (int)(idx >> 21);
  long r = (idx >> 5) & 65535;   // input row = b*2048 + s
  int c8 = (int)(idx & 31);
  long b = r >> 11, s = r & 2047;
  const float* src = (side ? graph : text) + r * 256 + c8 * 8;
  u16* dst = (side ? T2G : T2T) + ((s << 5) + b) * 256 + c8 * 8;
  f32x4 v0 = *(const f32x4*)src;
  f32x4 v1 = *(const f32x4*)(src + 4);
  s16x8 t;
  t[0] = (short)f2bf(2.f * v0[0]); t[1] = (short)f2bf(2.f * v0[1]);
  t[2] = (short)f2bf(2.f * v0[2]); t[3] = (short)f2bf(2.f * v0[3]);
  t[4] = (short)f2bf(2.f * v1[0]); t[5] = (short)f2bf(2.f * v1[1]);
  t[6] = (short)f2bf(2.f * v1[2]); t[7] = (short)f2bf(2.f * v1[3]);
  *(s16x8*)dst = t;
}

// =================================================================
// Phase 1: per-(s,side) block: K/Q/V proj -> QK^T -> softmax -> PV
// -> out-proj. 4096 blocks x 256 thr (4 waves).
// att output in (s,b,e) layout -> final write is one contiguous 16KB.
// =================================================================
#define AOo 0
#define AXo 8448
#define KBo 16896
#define QBo 25344
#define SFo 33792
#define PBo 35904
#define VTo 8448
#define OBo 25344
#define STo 16896

__global__ __launch_bounds__(256, 2) void k_attn(
    const u16* __restrict__ T2T, const u16* __restrict__ T2G,
    const u16* __restrict__ Wproj, const float* __restrict__ bproj,
    const u16* __restrict__ Wout, const float* __restrict__ bout,
    u16* __restrict__ attT, u16* __restrict__ attG) {
  __shared__ u16 sh[37184];
  int n = blockIdx.x, s = blockIdx.y;
  const u16* pown = (s ? T2G : T2T) + n * 8192;
  const u16* poth = (s ? T2T : T2G) + n * 8192;
  u16* dst = s ? attG : attT;
  int tid = threadIdx.x, w = tid >> 6, lane = tid & 63;
  int lr = lane & 15, kg = lane >> 4;
  int fro = ((kg << 4) + lr) * 8;  // in-fragment offset for packed B

  // ---- ph1: cooperative 16KB panel loads (coalesced) ----
  {
    int r = tid >> 3, c0 = (tid & 7) * 32;
    const u16* so = pown + r * 256 + c0;
    const u16* sx = poth + r * 256 + c0;
    u16* d0 = sh + AOo + r * 264 + c0;
    u16* d1 = sh + AXo + r * 264 + c0;
#pragma unroll
    for (int j = 0; j < 4; ++j) {
      *(s16x8*)(d0 + j * 8) = *(const s16x8*)(so + j * 8);
      *(s16x8*)(d1 + j * 8) = *(const s16x8*)(sx + j * 8);
    }
  }
  __syncthreads();

  s16x8 af[2][8];  // A fragments (AX for K, then AO for Q/V)

  // ---- ph2a: K-proj from other-side panel (W cols 256..511) ----
#pragma unroll
  for (int mt = 0; mt < 2; ++mt)
#pragma unroll
    for (int k = 0; k < 8; ++k)
      af[mt][k] = *(const s16x8*)(sh + AXo + (mt * 16 + lr) * 264 + k * 32 + kg * 8);
  for (int i = 0; i < 4; ++i) {
    int ct = 16 + w * 4 + i;
    const u16* wp = Wproj + (ct << 12) + fro;
    s16x8 b[8];
#pragma unroll
    for (int k = 0; k < 8; ++k) b[k] = *(const s16x8*)(wp + (k << 9));
    f32x4 a0 = Z4, a1 = Z4;
#pragma unroll
    for (int k = 0; k < 8; ++k) {
      a0 = MFMA16(af[0][k], b[k], a0);
      a1 = MFMA16(af[1][k], b[k], a1);
    }
    int colk = (ct << 4) + lr;
    float bias = bproj[colk];
    u16* base = sh + KBo + (colk - 256);
#pragma unroll
    for (int j = 0; j < 4; ++j) {
      base[(kg * 4 + j) * 264] = f2bf(a0[j] + bias);
      base[(16 + kg * 4 + j) * 264] = f2bf(a1[j] + bias);
    }
  }

  // ---- ph2b: Q-proj from own-side panel (W cols 0..255) ----
#pragma unroll
  for (int mt = 0; mt < 2; ++mt)
#pragma unroll
    for (int k = 0; k < 8; ++k)
      af[mt][k] = *(const s16x8*)(sh + AOo + (mt * 16 + lr) * 264 + k * 32 + kg * 8);
  for (int i = 0; i < 4; ++i) {
    int ct = w * 4 + i;
    const u16* wp = Wproj + (ct << 12) + fro;
    s16x8 b[8];
#pragma unroll
    for (int k = 0; k < 8; ++k) b[k] = *(const s16x8*)(wp + (k << 9));
    f32x4 a0 = Z4, a1 = Z4;
#pragma unroll
    for (int k = 0; k < 8; ++k) {
      a0 = MFMA16(af[0][k], b[k], a0);
      a1 = MFMA16(af[1][k], b[k], a1);
    }
    int colq = (ct << 4) + lr;
    float bias = bproj[colq];
    u16* base = sh + QBo + colq;
#pragma unroll
    for (int j = 0; j < 4; ++j) {
      base[(kg * 4 + j) * 264] = f2bf(a0[j] + bias);
      base[(16 + kg * 4 + j) * 264] = f2bf(a1[j] + bias);
    }
  }
  __syncthreads();

  // ---- ph3: scores S[l][m] = Q.K^T / 16 ----
  {
    int mt = w >> 1, nt = w & 1;
    f32x4 acc = Z4;
#pragma unroll
    for (int k = 0; k < 8; ++k) {
      s16x8 qa = *(const s16x8*)(sh + QBo + (mt * 16 + lr) * 264 + k * 32 + kg * 8);
      s16x8 kb = *(const s16x8*)(sh + KBo + (nt * 16 + lr) * 264 + k * 32 + kg * 8);
      acc = MFMA16(qa, kb, acc);
    }
    float* Sf = (float*)(sh + SFo);
#pragma unroll
    for (int j = 0; j < 4; ++j)
      Sf[(mt * 16 + kg * 4 + j) * 33 + nt * 16 + lr] = acc[j] * 0.0625f;
  }
  __syncthreads();

  // ---- ph4: V-proj (af=AO still live; W cols 512..767) + softmax ----
  for (int i = 0; i < 4; ++i) {
    int ct = 32 + w * 4 + i;
    const u16* wp = Wproj + (ct << 12) + fro;
    s16x8 b[8];
#pragma unroll
    for (int k = 0; k < 8; ++k) b[k] = *(const s16x8*)(wp + (k << 9));
    f32x4 a0 = Z4, a1 = Z4;
#pragma unroll
    for (int k = 0; k < 8; ++k) {
      a0 = MFMA16(af[0][k], b[k], a0);
      a1 = MFMA16(af[1][k], b[k], a1);
    }
    int colv = (ct << 4) + lr;
    float bias = bproj[colv];
    u16* base = sh + VTo + (colv - 512) * 40;
#pragma unroll
    for (int j = 0; j < 4; ++j) {
      base[kg * 4 + j] = f2bf(a0[j] + bias);
      base[16 + kg * 4 + j] = f2bf(a1[j] + bias);
    }
  }
  if (tid < 32) {
    float* Sp = (float*)(sh + SFo) + tid * 33;
    float mx = -1e30f;
#pragma unroll
    for (int m = 0; m < 32; ++m) mx = fmaxf(mx, Sp[m]);
    float e[32]; float sum = 0.f;
#pragma unroll
    for (int m = 0; m < 32; ++m) { e[m] = __expf(Sp[m] - mx); sum += e[m]; }
    float inv = rcpf_(sum);
    u16* Pp = sh + PBo + tid * 40;
#pragma unroll
    for (int m = 0; m < 32; ++m) Pp[m] = f2bf(e[m] * inv);
  }
  __syncthreads();

  // ---- ph5: PV: O = P.V -> OB ----
  {
    s16x8 pa0 = *(const s16x8*)(sh + PBo + lr * 40 + kg * 8);
    s16x8 pa1 = *(const s16x8*)(sh + PBo + (16 + lr) * 40 + kg * 8);
#pragma unroll
    for (int i = 0; i < 4; ++i) {
      int e0 = (w * 4 + i) * 16;
      s16x8 vb = *(const s16x8*)(sh + VTo + (e0 + lr) * 40 + kg * 8);
      f32x4 a0 = MFMA16(pa0, vb, Z4);
      f32x4 a1 = MFMA16(pa1, vb, Z4);
      u16* base = sh + OBo + e0 + lr;
#pragma unroll
      for (int j = 0; j < 4; ++j) {
        base[(kg * 4 + j) * 264] = f2bf(a0[j]);
        base[(16 + kg * 4 + j) * 264] = f2bf(a1[j]);
      }
    }
  }
  __syncthreads();

  // ---- ph6: out-proj -> ST staging -> ONE contiguous 16KB write ----
  {
    s16x8 ao[2][8];
#pragma unroll
    for (int mt = 0; mt < 2; ++mt)
#pragma unroll
      for (int k = 0; k < 8; ++k)
        ao[mt][k] = *(const s16x8*)(sh + OBo + (mt * 16 + lr) * 264 + k * 32 + kg * 8);
    for (int i = 0; i < 4; ++i) {
      int ct = w * 4 + i;
      const u16* wp = Wout + (ct << 12) + fro;
      s16x8 b[8];
#pragma unroll
      for (int k = 0; k < 8; ++k) b[k] = *(const s16x8*)(wp + (k << 9));
      f32x4 a0 = Z4, a1 = Z4;
#pragma unroll
      for (int k = 0; k < 8; ++k) {
        a0 = MFMA16(ao[0][k], b[k], a0);
        a1 = MFMA16(ao[1][k], b[k], a1);
      }
      int cb = (ct << 4) + lr;
      float bias = bout[cb];
      u16* base = sh + STo + cb;
#pragma unroll
      for (int j = 0; j < 4; ++j) {
        base[(kg * 4 + j) * 264] = f2bf(a0[j] + bias);
        base[(16 + kg * 4 + j) * 264] = f2bf(a1[j] + bias);
      }
    }
  }
  __syncthreads();
  {
    int r = tid >> 3, c0 = (tid & 7) * 32;
    u16* dr = dst + ((long)n << 13) + r * 256 + c0;  // (s,b,e): contiguous
#pragma unroll
    for (int j = 0; j < 4; ++j)
      *(s16x8*)(dr + j * 8) = *(const s16x8*)(sh + STo + r * 264 + c0 + j * 8);
  }
}

// =================================================================
// Phase 2: H=attT*attG (to LDS) -> gates (gi via folded Wcomb) -> GRU.
// 2048 blocks x 32 rows, 512 thr / 8 waves; wave = 32 rows x 32 cols,
// B reg-dbuf. H staged in HI LDS (NOT held in regs across the gate
// loop — that spilled in round 11: WRITE_SIZE 65->535MB).
// LDS: AT @0, AG @8448, HI @16896 = 50.7 KB.
// =================================================================
__global__ __launch_bounds__(512, 1) void k_gru(
    const u16* __restrict__ attT, const u16* __restrict__ attG,
    const u16* __restrict__ Wcomb, const float* __restrict__ bcomb,
    const u16* __restrict__ Whh, const float* __restrict__ bhh,
    u16* __restrict__ g1, u16* __restrict__ g2) {
  __shared__ u16 sh[25344];
  const int AT = 0, AG = 8448, HI = 16896;
  int m0 = blockIdx.x * 32;
  int tid = threadIdx.x, w = tid >> 6, lane = tid & 63;
  int lr = lane & 15, kg = lane >> 4;
  int fro = ((kg << 4) + lr) * 8;

  // cooperative att load (coalesced, non-temporal)
  {
    int r = tid >> 4, c0 = (tid & 15) * 16;
    const u16* pt = attT + (m0 + r) * 256 + c0;
    const u16* pg = attG + (m0 + r) * 256 + c0;
    *(s16x8*)(sh + AT + r * 264 + c0) = __builtin_nontemporal_load((const s16x8*)pt);
    *(s16x8*)(sh + AT + r * 264 + c0 + 8) = __builtin_nontemporal_load((const s16x8*)(pt + 8));
    *(s16x8*)(sh + AG + r * 264 + c0) = __builtin_nontemporal_load((const s16x8*)pg);
    *(s16x8*)(sh + AG + r * 264 + c0 + 8) = __builtin_nontemporal_load((const s16x8*)(pg + 8));
  }
  __syncthreads();

  // H = AT*AG elementwise -> HI (LDS), short register lifetimes
  {
    int r = tid >> 4, c0 = (tid & 15) * 16;
#pragma unroll
    for (int half = 0; half < 2; ++half) {
      s16x8 t8 = *(const s16x8*)(sh + AT + r * 264 + c0 + half * 8);
      s16x8 g8 = *(const s16x8*)(sh + AG + r * 264 + c0 + half * 8);
      s16x8 h;
#pragma unroll
      for (int j = 0; j < 8; ++j)
        h[j] = (short)f2bf(bf2f((u16)t8[j]) * bf2f((u16)g8[j]));
      *(s16x8*)(sh + HI + r * 264 + c0 + half * 8) = h;
    }
  }
  __syncthreads();

#define LDGATE(slot, kk) { \
    int fo_ = ((kk) << 9) + fro; \
    bI[slot][0] = *(const s16x8*)(Wcomb + (ct0 << 12) + fo_); \
    bI[slot][1] = *(const s16x8*)(Wcomb + (ct1 << 12) + fo_); \
    bI[slot][2] = *(const s16x8*)(Wcomb + (ct2 << 12) + fo_); \
    bH[slot][0] = *(const s16x8*)(Whh + (ct0 << 12) + fo_); \
    bH[slot][1] = *(const s16x8*)(Whh + (ct1 << 12) + fo_); \
    bH[slot][2] = *(const s16x8*)(Whh + (ct2 << 12) + fo_); }

  // gate GEMMs (B reg-dbuf) + GRU elementwise -> reg buffers
  s16x8 o1b[2], o2b[2];
#pragma unroll
  for (int ic = 0; ic < 2; ++ic) {
    int ct0 = w * 2 + ic, ct1 = 16 + ct0, ct2 = 32 + ct0;
    int col = (ct0 << 4) + lr;
    f32x4 acc[3][3][2];
#pragma unroll
    for (int g = 0; g < 3; ++g)
#pragma unroll
      for (int s2 = 0; s2 < 3; ++s2) { acc[g][s2][0] = Z4; acc[g][s2][1] = Z4; }
    s16x8 bI[2][3], bH[2][3];
    LDGATE(0, 0)
#pragma unroll
    for (int k = 0; k < 8; ++k) {
      const int c = k & 1, nx = c ^ 1;
      if (k < 7) { LDGATE(nx, k + 1) }
      int ko = k * 32 + kg * 8;
      s16x8 aI0 = *(const s16x8*)(sh + HI + lr * 264 + ko);
      s16x8 aI1 = *(const s16x8*)(sh + HI + (16 + lr) * 264 + ko);
      s16x8 aT0 = *(const s16x8*)(sh + AT + lr * 264 + ko);
      s16x8 aT1 = *(const s16x8*)(sh + AT + (16 + lr) * 264 + ko);
      s16x8 aG0 = *(const s16x8*)(sh + AG + lr * 264 + ko);
      s16x8 aG1 = *(const s16x8*)(sh + AG + (16 + lr) * 264 + ko);
#pragma unroll
      for (int g = 0; g < 3; ++g) {
        acc[g][0][0] = MFMA16(aI0, bI[c][g], acc[g][0][0]);
        acc[g][0][1] = MFMA16(aI1, bI[c][g], acc[g][0][1]);
        acc[g][1][0] = MFMA16(aT0, bH[c][g], acc[g][1][0]);
        acc[g][1][1] = MFMA16(aT1, bH[c][g], acc[g][1][1]);
        acc[g][2][0] = MFMA16(aG0, bH[c][g], acc[g][2][0]);
        acc[g][2][1] = MFMA16(aG1, bH[c][g], acc[g][2][1]);
      }
    }
    float bir = bcomb[col], biz = bcomb[col + 256], bin_ = bcomb[col + 512];
    float bhr = bhh[col], bhz = bhh[col + 256], bhn = bhh[col + 512];
    s16x8 o1v, o2v;
#pragma unroll
    for (int mt = 0; mt < 2; ++mt)
#pragma unroll
      for (int j = 0; j < 4; ++j) {
        int row = mt * 16 + kg * 4 + j;
        float hT = bf2f(sh[AT + row * 264 + col]);
        float hG = bf2f(sh[AG + row * 264 + col]);
        float ir = acc[0][0][mt][j] + bir;
        float iz = acc[1][0][mt][j] + biz;
        float inn = acc[2][0][mt][j] + bin_;
        float r1 = sigmoidf_(ir + acc[0][1][mt][j] + bhr);
        float z1 = sigmoidf_(iz + acc[1][1][mt][j] + bhz);
        float n1 = tanhf_(inn + r1 * (acc[2][1][mt][j] + bhn));
        o1v[mt * 4 + j] = (short)f2bf((1.f - z1) * n1 + z1 * hT);
        float r2 = sigmoidf_(ir + acc[0][2][mt][j] + bhr);
        float z2 = sigmoidf_(iz + acc[1][2][mt][j] + bhz);
        float n2 = tanhf_(inn + r2 * (acc[2][2][mt][j] + bhn));
        o2v[mt * 4 + j] = (short)f2bf((1.f - z2) * n2 + z2 * hG);
      }
    o1b[ic] = o1v; o2b[ic] = o2v;
  }
  __syncthreads();  // all AT/AG/HI reads complete

  // stage outputs into AT/AG (now dead), then coalesced global writes
#pragma unroll
  for (int ic = 0; ic < 2; ++ic) {
    int col = ((w * 2 + ic) << 4) + lr;
#pragma unroll
    for (int mt = 0; mt < 2; ++mt)
#pragma unroll
      for (int j = 0; j < 4; ++j) {
        int row = mt * 16 + kg * 4 + j;
        sh[AT + row * 264 + col] = (u16)o1b[ic][mt * 4 + j];
        sh[AG + row * 264 + col] = (u16)o2b[ic][mt * 4 + j];
      }
  }
  __syncthreads();
  {
    int r = tid >> 4, c0 = (tid & 15) * 16;
    u16* p1 = g1 + (long)(m0 + r) * 256 + c0;
    u16* p2 = g2 + (long)(m0 + r) * 256 + c0;
    *(s16x8*)(p1) = *(const s16x8*)(sh + AT + r * 264 + c0);
    *(s16x8*)(p1 + 8) = *(const s16x8*)(sh + AT + r * 264 + c0 + 8);
    *(s16x8*)(p2) = *(const s16x8*)(sh + AG + r * 264 + c0);
    *(s16x8*)(p2 + 8) = *(const s16x8*)(sh + AG + r * 264 + c0 + 8);
  }
}

// =================================================================
// Phase 3: out = relu(conv7x7(g1)+b) + relu(conv7x7(g2)+b), f32 out.
// g1/g2 are in (s,b,e) layout; out stays (b,s,e) f32.
// =================================================================
__global__ __launch_bounds__(256) void k_conv(
    const u16* __restrict__ g1, const u16* __restrict__ g2,
    const float* __restrict__ wss, const float* __restrict__ bss,
    float* __restrict__ out) {
  __shared__ float s1[38][73];
  __shared__ float s2[38][73];
  int et = blockIdx.x, st = blockIdx.y, b = blockIdx.z;
  int s0 = st * 32, e0 = et * 64;
  int tid = threadIdx.x;
  for (int idx = tid; idx < 38 * 70; idx += 256) {
    int r = idx / 70, c = idx % 70;
    int s = s0 + r - 3, e = e0 + c - 3;
    float v1 = 0.f, v2 = 0.f;
    if (s >= 0 && s < 2048 && e >= 0 && e < 256) {
      long off = ((long)s * 32 + b) * 256 + e;  // (s,b,e)
      v1 = bf2f(g1[off]); v2 = bf2f(g2[off]);
    }
    s1[r][c] = v1; s2[r][c] = v2;
  }
  __syncthreads();
  float bias = bss[0];
  int oy = tid >> 3, ox = (tid & 7) * 8;
  float a1[8] = {0.f, 0.f, 0.f, 0.f, 0.f, 0.f, 0.f, 0.f};
  float a2[8] = {0.f, 0.f, 0.f, 0.f, 0.f, 0.f, 0.f, 0.f};
#pragma unroll
  for (int ky = 0; ky < 7; ++ky) {
    float wr[7];
#pragma unroll
    for (int kx = 0; kx < 7; ++kx) wr[kx] = wss[ky * 7 + kx];
    float r1[14], r2[14];
#pragma unroll
    for (int j = 0; j < 14; ++j) { r1[j] = s1[oy + ky][ox + j]; r2[j] = s2[oy + ky][ox + j]; }
#pragma unroll
    for (int x = 0; x < 8; ++x)
#pragma unroll
      for (int kx = 0; kx < 7; ++kx) {
        a1[x] += r1[x + kx] * wr[kx];
        a2[x] += r2[x + kx] * wr[kx];
      }
  }
  long obase = ((long)b * 2048 + s0 + oy) * 256 + e0 + ox;
  f32x4 o0, o1;
#pragma unroll
  for (int x = 0; x < 4; ++x) {
    o0[x] = fmaxf(a1[x] + bias, 0.f) + fmaxf(a2[x] + bias, 0.f);
    o1[x] = fmaxf(a1[x + 4] + bias, 0.f) + fmaxf(a2[x + 4] + bias, 0.f);
  }
  *(f32x4*)(out + obase) = o0;
  *(f32x4*)(out + obase + 4) = o1;
}

extern "C" void kernel_launch(void* const* d_in, const int* in_sizes, int n_in,
                              void* d_out, int out_size, void* d_ws, size_t ws_size,
                              hipStream_t stream) {
  const float* text = (const float*)d_in[0];
  const float* graph = (const float*)d_in[1];
  // d_in[2..7] (avg_*/max_*/sp_*) are mathematically dead:
  // softmax over size-1 axes == 1 -> fused = 2*input exactly.
  const float* in_proj_w = (const float*)d_in[8];
  const float* in_proj_b = (const float*)d_in[9];
  const float* out_w = (const float*)d_in[10];
  const float* out_b = (const float*)d_in[11];
  const float* lin_w = (const float*)d_in[12];
  const float* lin_b = (const float*)d_in[13];
  const float* w_ih = (const float*)d_in[14];
  const float* w_hh = (const float*)d_in[15];
  const float* b_ih = (const float*)d_in[16];
  const float* b_hh = (const float*)d_in[17];
  const float* ssf_w = (const float*)d_in[18];
  const float* ssf_b = (const float*)d_in[19];

  // ws: g1 (32MB) | g2 (32MB) | packed bf16 weights (1.31MB) | bcomb f32
  // T2T/T2G (pre-transposed inputs) ALIAS g1/g2 (disjoint lifetimes).
  u16* g1 = (u16*)d_ws;
  u16* g2 = g1 + 16777216;
  u16* T2T = g1;
  u16* T2G = g2;
  u16* Wall = g2 + 16777216;
  u16* Wproj = Wall;                 // 196608
  u16* Wout = Wall + 196608;         // 65536
  u16* Wcomb = Wall + 262144;        // 196608 (Wih@Wlin, packed)
  u16* Whh = Wall + 458752;          // 196608
  float* bcomb = (float*)(Wall + 655360);  // 768 f32

  // d_out (64MB f32) doubles as bf16 scratch for attT/attG (s,b,e);
  // k_conv fully rewrites it as f32 at the end.
  u16* attT = (u16*)d_out;
  u16* attG = attT + 16777216;

  k_wconv<<<224, 256, 0, stream>>>(in_proj_w, out_w, w_hh, Wall);
  k_wcomb<<<768, 256, 0, stream>>>(w_ih, lin_w, lin_b, b_ih, Wcomb, bcomb);
  k_tr<<<16384, 256, 0, stream>>>(text, graph, T2T, T2G);

  k_attn<<<dim3(2048, 2), 256, 0, stream>>>(T2T, T2G, Wproj, in_proj_b, Wout, out_b, attT, attG);
  k_gru<<<2048, 512, 0, stream>>>(attT, attG, Wcomb, bcomb, Whh, b_hh, g1, g2);
  k_conv<<<dim3(4, 64, 32), 256, 0, stream>>>(g1, g2, ssf_w, ssf_b, (float*)d_out);
}